// Round 1
// baseline (450.263 us; speedup 1.0000x reference)
//
#include <hip/hip_runtime.h>
#include <math.h>

#define BB 32
#define TT 2048
#define SIN 1024
#define HIN 1024
#define KD 512
#define VD 512

// ws layout (float offsets)
#define OFF_Q      0                       // B*KD            = 16384
#define OFF_WPART  16384                   // 4*B*HIN         = 131072
#define OFF_W      147456                  // B*HIN           = 32768
#define OFF_E      180224                  // B*T             = 65536
#define OFF_PART   245760                  // 512*1028        = 526336
#define OFF_CTX    772096                  // B*HIN           = 32768
#define OFF_R      804864                  // B               = 32

__device__ __forceinline__ float dot4(float4 a, float4 b) {
  return fmaf(a.x, b.x, fmaf(a.y, b.y, fmaf(a.z, b.z, a.w * b.w)));
}

__device__ __forceinline__ float wave_reduce_sum(float e) {
#pragma unroll
  for (int off = 32; off > 0; off >>= 1) e += __shfl_xor(e, off, 64);
  return e;
}

// ---------------- Kernel 1a: q[b][k] = Ws[k,:]·ds[b,:] + bs[k] ----------------
__global__ __launch_bounds__(256) void k_query(const float* __restrict__ ds,
                                               const float* __restrict__ Ws,
                                               const float* __restrict__ bs,
                                               float* __restrict__ q) {
  const int lane = threadIdx.x & 63;
  const int wid  = threadIdx.x >> 6;
  const int k    = blockIdx.x * 4 + wid;   // grid 128 -> k in [0,512)
  const float4* Wr = (const float4*)(Ws + (size_t)k * SIN);
  float4 w0 = Wr[lane], w1 = Wr[64 + lane], w2 = Wr[128 + lane], w3 = Wr[192 + lane];
  float bk = bs[k];
  for (int b = 0; b < BB; ++b) {
    const float4* dr = (const float4*)(ds + (size_t)b * SIN);
    float4 d0 = dr[lane], d1 = dr[64 + lane], d2 = dr[128 + lane], d3 = dr[192 + lane];
    float e = dot4(w0, d0) + dot4(w1, d1) + dot4(w2, d2) + dot4(w3, d3);
    e = wave_reduce_sum(e);
    if (lane == 0) q[(size_t)b * KD + k] = e + bk;
  }
}

// ------------- Kernel 1b: wpart[z][b][h] partial of Wh^T q over k-chunk -------
__global__ __launch_bounds__(256) void k_wpart(const float* __restrict__ Wh,
                                               const float* __restrict__ q,
                                               float* __restrict__ wpart) {
  __shared__ float qs[8][128];
  const int h  = blockIdx.x * 256 + threadIdx.x;   // grid.x = 4
  const int b0 = blockIdx.y * 8;                   // grid.y = 4
  const int k0 = blockIdx.z * 128;                 // grid.z = 4
#pragma unroll
  for (int r = 0; r < 4; ++r) {
    int lin = r * 256 + threadIdx.x;
    qs[lin >> 7][lin & 127] = q[(size_t)(b0 + (lin >> 7)) * KD + k0 + (lin & 127)];
  }
  __syncthreads();
  float acc[8] = {0.f, 0.f, 0.f, 0.f, 0.f, 0.f, 0.f, 0.f};
  for (int kk = 0; kk < 128; ++kk) {
    float wh = Wh[(size_t)(k0 + kk) * HIN + h];
#pragma unroll
    for (int i = 0; i < 8; ++i) acc[i] = fmaf(wh, qs[i][kk], acc[i]);
  }
#pragma unroll
  for (int i = 0; i < 8; ++i)
    wpart[(size_t)blockIdx.z * (BB * HIN) + (size_t)(b0 + i) * HIN + h] = acc[i];
}

// ---------------- Kernel 1c: w[b][h] = sum_z wpart[z][b][h] -------------------
__global__ __launch_bounds__(256) void k_wred(const float* __restrict__ wpart,
                                              float* __restrict__ w) {
  const int b = blockIdx.x;  // grid 32
#pragma unroll
  for (int i = 0; i < 4; ++i) {
    int h = threadIdx.x + 256 * i;
    float s = 0.f;
#pragma unroll
    for (int z = 0; z < 4; ++z) s += wpart[(size_t)z * (BB * HIN) + (size_t)b * HIN + h];
    w[(size_t)b * HIN + h] = s;
  }
}

// ------------- Kernel 2: single pass over listener_output (268 MB) ------------
// grid 512: b = blk>>4, chunk = blk&15 (128 t each). 4 waves/block, online softmax.
__global__ __launch_bounds__(256) void k_main(const float* __restrict__ L,
                                              const float* __restrict__ wv,
                                              const int* __restrict__ lens,
                                              float* __restrict__ energy,
                                              float* __restrict__ part) {
  const int b     = blockIdx.x >> 4;
  const int chunk = blockIdx.x & 15;
  const int wid   = threadIdx.x >> 6;
  const int lane  = threadIdx.x & 63;
  const int len   = lens[b];
  const bool row0 = (b == 0);

  const float4* wr = (const float4*)(wv + (size_t)b * HIN);
  float4 w0 = wr[lane], w1 = wr[64 + lane], w2 = wr[128 + lane], w3 = wr[192 + lane];

  float m = -INFINITY, z = 0.f, kept = 0.f;
  float4 a0 = {0, 0, 0, 0}, a1 = {0, 0, 0, 0}, a2 = {0, 0, 0, 0}, a3 = {0, 0, 0, 0};
  const size_t rowbase = (size_t)b * TT * HIN;

  for (int i = 0; i < 32; ++i) {
    const int t = chunk * 128 + i * 4 + wid;
    const float4* vr = (const float4*)(L + rowbase + (size_t)t * HIN);
    float4 v0 = vr[lane], v1 = vr[64 + lane], v2 = vr[128 + lane], v3 = vr[192 + lane];
    float e = dot4(w0, v0) + dot4(w1, v1) + dot4(w2, v2) + dot4(w3, v3);
    e = wave_reduce_sum(e);
    if (lane == 0) energy[(size_t)b * TT + t] = e;
    if (e > m) {  // wave-uniform branch
      float sc = __expf(m - e);  // first iter: expf(-inf)=0
      z *= sc; kept *= sc;
      a0.x *= sc; a0.y *= sc; a0.z *= sc; a0.w *= sc;
      a1.x *= sc; a1.y *= sc; a1.z *= sc; a1.w *= sc;
      a2.x *= sc; a2.y *= sc; a2.z *= sc; a2.w *= sc;
      a3.x *= sc; a3.y *= sc; a3.z *= sc; a3.w *= sc;
      m = e;
    }
    float p = __expf(e - m);
    z += p;
    if (row0 || t < len) {  // wave-uniform
      kept += p;
      a0.x = fmaf(p, v0.x, a0.x); a0.y = fmaf(p, v0.y, a0.y);
      a0.z = fmaf(p, v0.z, a0.z); a0.w = fmaf(p, v0.w, a0.w);
      a1.x = fmaf(p, v1.x, a1.x); a1.y = fmaf(p, v1.y, a1.y);
      a1.z = fmaf(p, v1.z, a1.z); a1.w = fmaf(p, v1.w, a1.w);
      a2.x = fmaf(p, v2.x, a2.x); a2.y = fmaf(p, v2.y, a2.y);
      a2.z = fmaf(p, v2.z, a2.z); a2.w = fmaf(p, v2.w, a2.w);
      a3.x = fmaf(p, v3.x, a3.x); a3.y = fmaf(p, v3.y, a3.y);
      a3.z = fmaf(p, v3.z, a3.z); a3.w = fmaf(p, v3.w, a3.w);
    }
  }

  // block combine of the 4 wave partials
  __shared__ float hdr[4][3];
  __shared__ float accs[4][1024];
  if (lane == 0) { hdr[wid][0] = m; hdr[wid][1] = z; hdr[wid][2] = kept; }
  float4* as = (float4*)accs[wid];
  as[lane] = a0; as[64 + lane] = a1; as[128 + lane] = a2; as[192 + lane] = a3;
  __syncthreads();
  float M = fmaxf(fmaxf(hdr[0][0], hdr[1][0]), fmaxf(hdr[2][0], hdr[3][0]));
  float sc_[4]; float Z = 0.f, K = 0.f;
#pragma unroll
  for (int w = 0; w < 4; ++w) {
    float s = __expf(hdr[w][0] - M);
    sc_[w] = s; Z = fmaf(hdr[w][1], s, Z); K = fmaf(hdr[w][2], s, K);
  }
  float* pb = part + (size_t)blockIdx.x * 1028;
  if (threadIdx.x == 0) { pb[0] = M; pb[1] = Z; pb[2] = K; }
#pragma unroll
  for (int i = 0; i < 4; ++i) {
    int h = threadIdx.x + 256 * i;
    float A = accs[0][h] * sc_[0] + accs[1][h] * sc_[1] +
              accs[2][h] * sc_[2] + accs[3][h] * sc_[3];
    pb[4 + h] = A;
  }
}

// ------- Kernel 3: per-row reduce, ctx_h, r_b, and attn output ---------------
__global__ __launch_bounds__(256) void k_reduce(const float* __restrict__ part,
                                                const float* __restrict__ energy,
                                                const int* __restrict__ lens,
                                                float* __restrict__ ctx,
                                                float* __restrict__ rb,
                                                float* __restrict__ out_attn) {
  const int b = blockIdx.x;  // grid 32
  __shared__ float sM[16], sZ[16], sK[16];
  if (threadIdx.x < 16) {
    const float* pb = part + (size_t)(b * 16 + threadIdx.x) * 1028;
    sM[threadIdx.x] = pb[0]; sZ[threadIdx.x] = pb[1]; sK[threadIdx.x] = pb[2];
  }
  __syncthreads();
  float M = -INFINITY;
#pragma unroll
  for (int i = 0; i < 16; ++i) M = fmaxf(M, sM[i]);
  float scl[16]; float Z = 0.f, K = 0.f;
#pragma unroll
  for (int i = 0; i < 16; ++i) {
    float s = __expf(sM[i] - M);
    scl[i] = s; Z = fmaf(sZ[i], s, Z); K = fmaf(sK[i], s, K);
  }
  const float kept_sum = K / Z;                 // sum of masked softmax probs
  const float ks = fmaxf(kept_sum, 1e-12f);     // F.normalize eps clamp
  const float inv = 1.f / (Z * ks);
  // ctx_h
#pragma unroll
  for (int i = 0; i < 4; ++i) {
    int h = threadIdx.x + 256 * i;
    float A = 0.f;
#pragma unroll
    for (int p = 0; p < 16; ++p)
      A = fmaf(part[(size_t)(b * 16 + p) * 1028 + 4 + h], scl[p], A);
    ctx[(size_t)b * HIN + h] = A * inv;
  }
  // attn output
  const int len = lens[b];
#pragma unroll
  for (int i = 0; i < 8; ++i) {
    int t = threadIdx.x + 256 * i;
    bool keep = (b == 0) || (t < len);
    float e = energy[(size_t)b * TT + t];
    out_attn[(size_t)b * TT + t] = keep ? __expf(e - M) * inv : 0.f;
  }
  if (threadIdx.x == 0) rb[b] = kept_sum / ks;  // == sum(attn) after renorm
}

// --------- Kernel 4: context[b][v] = Wv[v,:]·ctx_h[b,:] + bv[v]*r_b ----------
__global__ __launch_bounds__(256) void k_context(const float* __restrict__ Wvm,
                                                 const float* __restrict__ bv,
                                                 const float* __restrict__ ctx,
                                                 const float* __restrict__ rb,
                                                 float* __restrict__ out) {
  const int lane = threadIdx.x & 63;
  const int wid  = threadIdx.x >> 6;
  const int v    = blockIdx.x * 4 + wid;  // grid 128 -> v in [0,512)
  const float4* Wr = (const float4*)(Wvm + (size_t)v * HIN);
  float4 w0 = Wr[lane], w1 = Wr[64 + lane], w2 = Wr[128 + lane], w3 = Wr[192 + lane];
  const float bvv = bv[v];
  for (int b = 0; b < BB; ++b) {
    const float4* cr = (const float4*)(ctx + (size_t)b * HIN);
    float4 c0 = cr[lane], c1 = cr[64 + lane], c2 = cr[128 + lane], c3 = cr[192 + lane];
    float e = dot4(w0, c0) + dot4(w1, c1) + dot4(w2, c2) + dot4(w3, c3);
    e = wave_reduce_sum(e);
    if (lane == 0) out[(size_t)b * VD + v] = e + bvv * rb[b];
  }
}

extern "C" void kernel_launch(void* const* d_in, const int* in_sizes, int n_in,
                              void* d_out, int out_size, void* d_ws, size_t ws_size,
                              hipStream_t stream) {
  const float* ds   = (const float*)d_in[0];
  const float* L    = (const float*)d_in[1];
  const int*   lens = (const int*)d_in[2];
  const float* Ws   = (const float*)d_in[3];
  const float* bs   = (const float*)d_in[4];
  const float* Wh   = (const float*)d_in[5];
  // d_in[6] = bh: adds a per-row constant to energies -> softmax-invariant, unused
  const float* Wv   = (const float*)d_in[7];
  const float* bv   = (const float*)d_in[8];
  float* out = (float*)d_out;
  float* ws  = (float*)d_ws;

  float* q      = ws + OFF_Q;
  float* wpart  = ws + OFF_WPART;
  float* w      = ws + OFF_W;
  float* energy = ws + OFF_E;
  float* part   = ws + OFF_PART;
  float* ctx    = ws + OFF_CTX;
  float* rbuf   = ws + OFF_R;

  k_query  <<<128, 256, 0, stream>>>(ds, Ws, bs, q);
  k_wpart  <<<dim3(4, 4, 4), 256, 0, stream>>>(Wh, q, wpart);
  k_wred   <<<32, 256, 0, stream>>>(wpart, w);
  k_main   <<<512, 256, 0, stream>>>(L, w, lens, energy, part);
  k_reduce <<<32, 256, 0, stream>>>(part, energy, lens, ctx, rbuf, out + BB * VD);
  k_context<<<128, 256, 0, stream>>>(Wv, bv, ctx, rbuf, out);
}